// Round 14
// baseline (667.295 us; speedup 1.0000x reference)
//
#include <hip/hip_runtime.h>

#define N_NODES 8192
#define D_IN 512
#define D_OUT 64
#define LRELU_ALPHA 0.2f
#define KSPLIT 4
#define KSLICE (N_NODES / KSPLIT)   // 2048 cols per block
#define NCHUNK (KSLICE / 128)       // 16 chunks of 128 cols

typedef __attribute__((ext_vector_type(8))) short bf16x8;
typedef __attribute__((ext_vector_type(4))) float f32x4;

__device__ __forceinline__ unsigned short f2bf(float x) {
    unsigned u = __float_as_uint(x);
    u += 0x7fffu + ((u >> 16) & 1u);   // round-to-nearest-even
    return (unsigned short)(u >> 16);
}

// exact pack of two {0.0,1.0} floats into two bf16 halfwords (no rounding needed)
__device__ __forceinline__ unsigned pk(float x, float y) {
    return (__float_as_uint(x) >> 16) | (__float_as_uint(y) & 0xFFFF0000u);
}

__device__ __forceinline__ bf16x8 mk8(unsigned a, unsigned b, unsigned c, unsigned d) {
    union { unsigned u[4]; bf16x8 v; } t;
    t.u[0] = a; t.u[1] = b; t.u[2] = c; t.u[3] = d;
    return t.v;
}

// ---------------- Kernel 1: Wh = h @ W; epilogue writes VpT/VnT (bf16 frag-order), tables ----------------
// VpT[f][col] = bf16(exp(Wh2[col]) * Wh[col][f]), VnT with exp(0.2*Wh2). Frag-order per
// 64-col block: shorts [(m>>1)*32 + g*8 + (m&1)*4 + d], col_in_block = g*4 + 16m + d
// -> each MFMA B fragment is one contiguous 16B at f*N + k + g*8.
__global__ __launch_bounds__(256) void k_gemm_wh(const float* __restrict__ h,
                                                 const float* __restrict__ W,
                                                 const float* __restrict__ a,
                                                 unsigned short* __restrict__ VpT,
                                                 unsigned short* __restrict__ VnT,
                                                 float* __restrict__ Wh1,
                                                 float* __restrict__ Wh2,
                                                 float* __restrict__ E1p,
                                                 float* __restrict__ E1n,
                                                 float* __restrict__ E2p,
                                                 float* __restrict__ E2n) {
    __shared__ float hs[32][68];
    __shared__ float Ws[64][64];
    const int tid = threadIdx.x;
    const int r0 = blockIdx.x * 32;
    const int tf = tid & 15;
    const int tr = tid >> 4;
    float acc[2][4] = {{0.f,0.f,0.f,0.f},{0.f,0.f,0.f,0.f}};

    for (int kc = 0; kc < D_IN; kc += 64) {
        {
            int rr = tid >> 4;
            int cc = (tid & 15) * 4;
            float4 v0 = *(const float4*)&h[(size_t)(r0 + rr) * D_IN + kc + cc];
            float4 v1 = *(const float4*)&h[(size_t)(r0 + rr + 16) * D_IN + kc + cc];
            *(float4*)&hs[rr][cc] = v0;
            *(float4*)&hs[rr + 16][cc] = v1;
        }
        #pragma unroll
        for (int p = 0; p < 4; ++p) {
            int kk = (tid >> 4) + p * 16;
            int cc = (tid & 15) * 4;
            *(float4*)&Ws[kk][cc] = *(const float4*)&W[(size_t)(kc + kk) * D_OUT + cc];
        }
        __syncthreads();
        #pragma unroll
        for (int k = 0; k < 64; k += 4) {
            float4 a0 = *(const float4*)&hs[tr*2][k];
            float4 a1 = *(const float4*)&hs[tr*2+1][k];
            float av0[4] = {a0.x, a0.y, a0.z, a0.w};
            float av1[4] = {a1.x, a1.y, a1.z, a1.w};
            #pragma unroll
            for (int kk = 0; kk < 4; ++kk) {
                float4 b = *(const float4*)&Ws[k+kk][tf*4];
                acc[0][0] += av0[kk]*b.x; acc[0][1] += av0[kk]*b.y;
                acc[0][2] += av0[kk]*b.z; acc[0][3] += av0[kk]*b.w;
                acc[1][0] += av1[kk]*b.x; acc[1][1] += av1[kk]*b.y;
                acc[1][2] += av1[kk]*b.z; acc[1][3] += av1[kk]*b.w;
            }
        }
        __syncthreads();
    }
    const int orow = r0 + tr*2;   // even

    // Wh1/Wh2 for the two rows (butterfly leaves the total in ALL 16 lanes)
    float a1v[4], a2v[4];
    #pragma unroll
    for (int k = 0; k < 4; ++k) { a1v[k] = a[tf*4 + k]; a2v[k] = a[64 + tf*4 + k]; }
    float s1 = 0.f, t1 = 0.f, s2 = 0.f, t2 = 0.f;
    #pragma unroll
    for (int k = 0; k < 4; ++k) {
        s1 += acc[0][k] * a1v[k];
        t1 += acc[1][k] * a1v[k];
        s2 += acc[0][k] * a2v[k];
        t2 += acc[1][k] * a2v[k];
    }
    #pragma unroll
    for (int d = 1; d < 16; d <<= 1) {
        s1 += __shfl_xor(s1, d);
        t1 += __shfl_xor(t1, d);
        s2 += __shfl_xor(s2, d);
        t2 += __shfl_xor(t2, d);
    }

    const float e2p0 = __expf(s2), e2p1 = __expf(t2);
    const float e2n0 = __expf(LRELU_ALPHA * s2), e2n1 = __expf(LRELU_ALPHA * t2);

    // permuted VpT/VnT write: cols (orow, orow+1) pack into one 4B store
    {
        const int blk = orow >> 6;
        const int cw  = orow & 63;
        const int d   = cw & 3;
        const int gg  = (cw >> 2) & 3;
        const int m   = cw >> 4;
        const int soff = blk * 64 + (m >> 1) * 32 + gg * 8 + (m & 1) * 4 + d;
        #pragma unroll
        for (int k = 0; k < 4; ++k) {
            unsigned vp = (unsigned)f2bf(e2p0 * acc[0][k]) | ((unsigned)f2bf(e2p1 * acc[1][k]) << 16);
            unsigned vn = (unsigned)f2bf(e2n0 * acc[0][k]) | ((unsigned)f2bf(e2n1 * acc[1][k]) << 16);
            *(unsigned*)&VpT[(size_t)(tf*4 + k) * N_NODES + soff] = vp;
            *(unsigned*)&VnT[(size_t)(tf*4 + k) * N_NODES + soff] = vn;
        }
    }

    if (tf == 0) {
        Wh1[orow] = s1; Wh1[orow + 1] = t1;
        Wh2[orow] = s2; Wh2[orow + 1] = t2;
        E1p[orow] = __expf(s1);              E1p[orow + 1] = __expf(t1);
        E1n[orow] = __expf(LRELU_ALPHA*s1);  E1n[orow + 1] = __expf(LRELU_ALPHA*t1);
        E2p[orow] = e2p0; E2p[orow + 1] = e2p1;
        E2n[orow] = e2n0; E2n[orow + 1] = e2n1;
    }
}

// ---------------- Kernel 2: fused mask-stream -> {0/1 GEMM x2} masked-softmax + PV ----------------
// exp-factorization: p_ij = mk * (t>0 ? E1p_i*E2p_j : E1n_i*E2n_j), t = Wh1_i + Wh2_j.
// A-fragments are EXACT 0/1 bf16 (a = mk*[t>0], b = mk - a): per element = cmp + cndmask
// + sub + 2 fma + pack -- no exp, no rounding. out = diag(E1p)*(A@Vp) + diag(E1n)*(B@Vn).
// Feature-split waves (wave w = features 16w..16w+15, all cols): acc = 8 VGPR total ->
// __launch_bounds__(256,4) -> 16 waves/CU (2x all prior rounds; TLP was the diagnosed gap:
// even the cache-resident R6 variant cost ~95us at 8 waves/CU). LDS = 16KB mask dbuf only.
__global__ __launch_bounds__(256, 4) void k_fused(const float* __restrict__ mask,
                                                  const unsigned short* __restrict__ VpT,
                                                  const unsigned short* __restrict__ VnT,
                                                  const float* __restrict__ Wh1,
                                                  const float* __restrict__ Wh2,
                                                  const float* __restrict__ E2p,
                                                  const float* __restrict__ E2n,
                                                  const float* __restrict__ E1p,
                                                  const float* __restrict__ E1n,
                                                  float* __restrict__ pacc,
                                                  float* __restrict__ plsum) {
    __shared__ float mbuf[2][16][128];   // 16 KB [par][row][swizzled col]

    const int tid  = threadIdx.x;
    const int wave = tid >> 6;
    const int lane = tid & 63;
    const int i16 = lane & 15;
    const int g   = lane >> 4;
    const int rowblk = blockIdx.x >> 2;
    const int slice  = blockIdx.x & 3;
    const int R     = rowblk * 16;
    const int kbase = slice * KSLICE;

    const float nw1 = -Wh1[R + i16];   // t>0  <=>  Wh2_j > nw1

    f32x4 accA = {0.f,0.f,0.f,0.f}, accB = {0.f,0.f,0.f,0.f};
    float lsA = 0.f, lsB = 0.f;

    // DMA chunk c (16 rows x 128 cols = 8KB) into parity p; wave w stages rows 4w..4w+3
    // (2 instrs x 1KB, each = 2 rows); per-lane source col XOR-swizzled by row&7.
#define DMA(c, p)                                                                       \
    {                                                                                   \
        const int r0_ = 4*wave + (lane >> 5);                                           \
        const int r1_ = r0_ + 2;                                                        \
        const float* s0_ = mask + (size_t)(R + r0_) * N_NODES + kbase + (c) * 128       \
                         + (((lane & 31) ^ (r0_ & 7)) << 2);                            \
        const float* s1_ = mask + (size_t)(R + r1_) * N_NODES + kbase + (c) * 128       \
                         + (((lane & 31) ^ (r1_ & 7)) << 2);                            \
        __builtin_amdgcn_global_load_lds(s0_, &mbuf[p][4*wave][0],     16, 0, 0);       \
        __builtin_amdgcn_global_load_lds(s1_, &mbuf[p][4*wave + 2][0], 16, 0, 0);       \
    }

    DMA(0, 0);
    __syncthreads();

    #pragma unroll 2
    for (int c = 0; c < NCHUNK; ++c) {
        const int par = c & 1;
        const int sw = i16 & 7;
        const int cb = kbase + c * 128;

        if (c + 1 < NCHUNK) DMA(c + 1, par ^ 1);

        #pragma unroll
        for (int q = 0; q < 4; ++q) {
            const int grlo = 8*q + g, grhi = grlo + 4;
            const float4 Ml = *(const float4*)&mbuf[par][i16][(grlo ^ sw) << 2];
            const float4 Mh = *(const float4*)&mbuf[par][i16][(grhi ^ sw) << 2];
            const float4 Wl = *(const float4*)&Wh2[cb + (grlo << 2)];
            const float4 Wh_ = *(const float4*)&Wh2[cb + (grhi << 2)];
            const float4 Pl = *(const float4*)&E2p[cb + (grlo << 2)];
            const float4 Ph = *(const float4*)&E2p[cb + (grhi << 2)];
            const float4 Nl = *(const float4*)&E2n[cb + (grlo << 2)];
            const float4 Nh = *(const float4*)&E2n[cb + (grhi << 2)];

            const float a0 = (Wl.x > nw1) ? Ml.x : 0.f;
            const float a1 = (Wl.y > nw1) ? Ml.y : 0.f;
            const float a2 = (Wl.z > nw1) ? Ml.z : 0.f;
            const float a3 = (Wl.w > nw1) ? Ml.w : 0.f;
            const float a4 = (Wh_.x > nw1) ? Mh.x : 0.f;
            const float a5 = (Wh_.y > nw1) ? Mh.y : 0.f;
            const float a6 = (Wh_.z > nw1) ? Mh.z : 0.f;
            const float a7 = (Wh_.w > nw1) ? Mh.w : 0.f;
            const float b0 = Ml.x - a0, b1 = Ml.y - a1, b2 = Ml.z - a2, b3 = Ml.w - a3;
            const float b4 = Mh.x - a4, b5 = Mh.y - a5, b6 = Mh.z - a6, b7 = Mh.w - a7;

            lsA = fmaf(a0, Pl.x, fmaf(a1, Pl.y, fmaf(a2, Pl.z, fmaf(a3, Pl.w, lsA))));
            lsA = fmaf(a4, Ph.x, fmaf(a5, Ph.y, fmaf(a6, Ph.z, fmaf(a7, Ph.w, lsA))));
            lsB = fmaf(b0, Nl.x, fmaf(b1, Nl.y, fmaf(b2, Nl.z, fmaf(b3, Nl.w, lsB))));
            lsB = fmaf(b4, Nh.x, fmaf(b5, Nh.y, fmaf(b6, Nh.z, fmaf(b7, Nh.w, lsB))));

            const bf16x8 afa = mk8(pk(a0,a1), pk(a2,a3), pk(a4,a5), pk(a6,a7));
            const bf16x8 afb = mk8(pk(b0,b1), pk(b2,b3), pk(b4,b5), pk(b6,b7));

            const size_t boff = (size_t)(wave*16 + i16) * N_NODES + cb + 32*q + g*8;
            const bf16x8 Bp = *(const bf16x8*)(VpT + boff);
            const bf16x8 Bn = *(const bf16x8*)(VnT + boff);

            accA = __builtin_amdgcn_mfma_f32_16x16x32_bf16(afa, Bp, accA, 0, 0, 0);
            accB = __builtin_amdgcn_mfma_f32_16x16x32_bf16(afb, Bn, accB, 0, 0, 0);
        }

        __syncthreads();   // DMA(c+1) landed; mbuf[par] free for c+2
    }
#undef DMA

    // per-row lsum: combine the 4 g-subgroups (xor 16/32 varies g only)
    lsA += __shfl_xor(lsA, 16);  lsA += __shfl_xor(lsA, 32);
    lsB += __shfl_xor(lsB, 16);  lsB += __shfl_xor(lsB, 32);

    // D layout (m89): out[mask-row 4g+r][feature wave*16+i16]; apply E1 row scales
    #pragma unroll
    for (int r = 0; r < 4; ++r) {
        const int row = R + 4*g + r;
        const float v = accA[r] * E1p[row] + accB[r] * E1n[row];
        pacc[((size_t)slice * N_NODES + row) * D_OUT + wave*16 + i16] = v;
    }
    if (tid < 16) {
        plsum[(size_t)slice * N_NODES + R + tid] =
            E1p[R + tid] * lsA + E1n[R + tid] * lsB;
    }
}

// ---------------- Kernel 3: sum KSPLIT partials, normalize, ELU ----------------
__global__ __launch_bounds__(256) void k_finish(const float* __restrict__ pacc,
                                                const float* __restrict__ plsum,
                                                float* __restrict__ out) {
    const int idx = blockIdx.x * 256 + threadIdx.x;
    const int row = idx >> 4;
    const int tf4 = (idx & 15) * 4;
    float4 s = {0.f, 0.f, 0.f, 0.f};
    float L = 0.f;
    #pragma unroll
    for (int k = 0; k < KSPLIT; ++k) {
        float4 v = *(const float4*)&pacc[((size_t)k * N_NODES + row) * D_OUT + tf4];
        s.x += v.x; s.y += v.y; s.z += v.z; s.w += v.w;
        L += plsum[(size_t)k * N_NODES + row];
    }
    const float inv = (L > 0.f) ? 1.f / L : 0.f;
    float4 o;
    o.x = s.x * inv; o.y = s.y * inv; o.z = s.z * inv; o.w = s.w * inv;
    o.x = (o.x > 0.f) ? o.x : (__expf(o.x) - 1.f);
    o.y = (o.y > 0.f) ? o.y : (__expf(o.y) - 1.f);
    o.z = (o.z > 0.f) ? o.z : (__expf(o.z) - 1.f);
    o.w = (o.w > 0.f) ? o.w : (__expf(o.w) - 1.f);
    *(float4*)&out[(size_t)row * D_OUT + tf4] = o;
}

extern "C" void kernel_launch(void* const* d_in, const int* in_sizes, int n_in,
                              void* d_out, int out_size, void* d_ws, size_t ws_size,
                              hipStream_t stream) {
    const float* h    = (const float*)d_in[0];
    const float* mask = (const float*)d_in[1];
    // d_in[2] = lamda: unused (dischange==0 makes the mask-update a no-op)
    const float* W    = (const float*)d_in[3];
    const float* a    = (const float*)d_in[4];
    float* out = (float*)d_out;

    // ws: VpT 1MB | VnT 1MB | Wh1,Wh2,E1p,E1n,E2p,E2n (6x32KB) | pacc 8MB | plsum 128KB
    unsigned short* VpT = (unsigned short*)d_ws;
    unsigned short* VnT = VpT + (size_t)D_OUT * N_NODES;
    float* Wh1 = (float*)(VnT + (size_t)D_OUT * N_NODES);
    float* Wh2 = Wh1 + N_NODES;
    float* E1p = Wh2 + N_NODES;
    float* E1n = E1p + N_NODES;
    float* E2p = E1n + N_NODES;
    float* E2n = E2p + N_NODES;
    float* pacc = E2n + N_NODES;
    float* plsum = pacc + (size_t)KSPLIT * N_NODES * D_OUT;

    k_gemm_wh<<<N_NODES / 32, 256, 0, stream>>>(h, W, a, VpT, VnT, Wh1, Wh2, E1p, E1n, E2p, E2n);
    k_fused<<<(N_NODES / 16) * KSPLIT, 256, 0, stream>>>(mask, VpT, VnT, Wh1, Wh2, E2p, E2n, E1p, E1n, pacc, plsum);
    k_finish<<<(N_NODES * D_OUT / 4) / 256, 256, 0, stream>>>(pacc, plsum, out);
}

// Round 15
// 143.693 us; speedup vs baseline: 4.6439x; 4.6439x over previous
//
#include <hip/hip_runtime.h>

#define N_NODES 8192
#define D_IN 512
#define D_OUT 64
#define LRELU_ALPHA 0.2f

typedef __attribute__((ext_vector_type(8))) short bf16x8;
typedef __attribute__((ext_vector_type(4))) float f32x4;

__device__ __forceinline__ unsigned short f2bf(float x) {
    unsigned u = __float_as_uint(x);
    u += 0x7fffu + ((u >> 16) & 1u);   // round-to-nearest-even
    return (unsigned short)(u >> 16);
}

// bit-gated p: e = lrelu(wh1+w2); p = bit ? exp(e) : 0
__device__ __forceinline__ float pb(unsigned bits, int pos, float w2v, float wh1v, float& lsum) {
    float e = wh1v + w2v;
    e = fmaxf(e, LRELU_ALPHA * e);
    float p = ((bits >> pos) & 1u) ? __expf(e) : 0.f;
    lsum += p;
    return p;
}

// ---------------- Kernel 0: mask f32 (256MB) -> natural-order bitmask (8MB) ----------------
// Lane l reads col base+64s+l -> ballot(s) is the u64 for cols [base+64s, base+64s+64) in
// NATURAL bit order. Layout: bits[strip][cc][row16], strip=row>>4, cc=col>>6 -> consumer
// wave reads 16 contiguous u64 (128B). Pure stream: tiny VGPR, full occupancy, BW-bound.
__global__ __launch_bounds__(256) void k_maskbits(const float* __restrict__ mask,
                                                  unsigned long long* __restrict__ bits) {
    const int wave = threadIdx.x >> 6;
    const int lane = threadIdx.x & 63;
    const int row = blockIdx.x * 4 + wave;
    const float* mrow = mask + (size_t)row * N_NODES;
    unsigned long long* bbase = bits + (size_t)(row >> 4) * 2048 + (row & 15);
    #pragma unroll 4
    for (int it = 0; it < 32; ++it) {
        const int base = it * 256;
        const float m0 = mrow[base + lane];
        const float m1 = mrow[base + 64 + lane];
        const float m2 = mrow[base + 128 + lane];
        const float m3 = mrow[base + 192 + lane];
        const unsigned long long b0 = __ballot(m0 > 0.f);
        const unsigned long long b1 = __ballot(m1 > 0.f);
        const unsigned long long b2 = __ballot(m2 > 0.f);
        const unsigned long long b3 = __ballot(m3 > 0.f);
        if (lane == 0) {
            bbase[(size_t)(it * 4 + 0) * 16] = b0;
            bbase[(size_t)(it * 4 + 1) * 16] = b1;
            bbase[(size_t)(it * 4 + 2) * 16] = b2;
            bbase[(size_t)(it * 4 + 3) * 16] = b3;
        }
    }
}

// ---------------- Kernel 1: Wh = h @ W; epilogue writes WhTp(bf16, frag-order), Wh1, Wh2 ----------------
__global__ __launch_bounds__(256) void k_gemm_wh(const float* __restrict__ h,
                                                 const float* __restrict__ W,
                                                 const float* __restrict__ a,
                                                 unsigned short* __restrict__ WhTp,
                                                 float* __restrict__ Wh1,
                                                 float* __restrict__ Wh2) {
    __shared__ float hs[32][68];
    __shared__ float Ws[64][64];
    const int tid = threadIdx.x;
    const int r0 = blockIdx.x * 32;
    const int tf = tid & 15;
    const int tr = tid >> 4;
    float acc[2][4] = {{0.f,0.f,0.f,0.f},{0.f,0.f,0.f,0.f}};

    for (int kc = 0; kc < D_IN; kc += 64) {
        {
            int rr = tid >> 4;
            int cc = (tid & 15) * 4;
            float4 v0 = *(const float4*)&h[(size_t)(r0 + rr) * D_IN + kc + cc];
            float4 v1 = *(const float4*)&h[(size_t)(r0 + rr + 16) * D_IN + kc + cc];
            *(float4*)&hs[rr][cc] = v0;
            *(float4*)&hs[rr + 16][cc] = v1;
        }
        #pragma unroll
        for (int p = 0; p < 4; ++p) {
            int kk = (tid >> 4) + p * 16;
            int cc = (tid & 15) * 4;
            *(float4*)&Ws[kk][cc] = *(const float4*)&W[(size_t)(kc + kk) * D_OUT + cc];
        }
        __syncthreads();
        #pragma unroll
        for (int k = 0; k < 64; k += 4) {
            float4 a0 = *(const float4*)&hs[tr*2][k];
            float4 a1 = *(const float4*)&hs[tr*2+1][k];
            float av0[4] = {a0.x, a0.y, a0.z, a0.w};
            float av1[4] = {a1.x, a1.y, a1.z, a1.w};
            #pragma unroll
            for (int kk = 0; kk < 4; ++kk) {
                float4 b = *(const float4*)&Ws[k+kk][tf*4];
                acc[0][0] += av0[kk]*b.x; acc[0][1] += av0[kk]*b.y;
                acc[0][2] += av0[kk]*b.z; acc[0][3] += av0[kk]*b.w;
                acc[1][0] += av1[kk]*b.x; acc[1][1] += av1[kk]*b.y;
                acc[1][2] += av1[kk]*b.z; acc[1][3] += av1[kk]*b.w;
            }
        }
        __syncthreads();
    }
    const int orow = r0 + tr*2;   // even

    // permuted WhTp write: each MFMA B fragment is one contiguous 16B
    {
        const int blk = orow >> 6;
        const int cw  = orow & 63;
        const int d   = cw & 3;
        const int gg  = (cw >> 2) & 3;
        const int m   = cw >> 4;
        const int soff = blk * 64 + (m >> 1) * 32 + gg * 8 + (m & 1) * 4 + d;
        #pragma unroll
        for (int k = 0; k < 4; ++k) {
            unsigned v = (unsigned)f2bf(acc[0][k]) | ((unsigned)f2bf(acc[1][k]) << 16);
            *(unsigned*)&WhTp[(size_t)(tf*4 + k) * N_NODES + soff] = v;
        }
    }

    float a1v[4], a2v[4];
    #pragma unroll
    for (int k = 0; k < 4; ++k) { a1v[k] = a[tf*4 + k]; a2v[k] = a[64 + tf*4 + k]; }
    float s1 = 0.f, t1 = 0.f, s2 = 0.f, t2 = 0.f;
    #pragma unroll
    for (int k = 0; k < 4; ++k) {
        s1 += acc[0][k] * a1v[k];
        t1 += acc[1][k] * a1v[k];
        s2 += acc[0][k] * a2v[k];
        t2 += acc[1][k] * a2v[k];
    }
    #pragma unroll
    for (int d = 1; d < 16; d <<= 1) {
        s1 += __shfl_xor(s1, d);
        t1 += __shfl_xor(t1, d);
        s2 += __shfl_xor(s2, d);
        t2 += __shfl_xor(t2, d);
    }
    if (tf == 0) {
        Wh1[orow] = s1; Wh1[orow + 1] = t1;
        Wh2[orow] = s2; Wh2[orow + 1] = t2;
    }
}

// ---------------- Kernel 2: bit-gated masked-softmax + PV via MFMA (no LDS loop, no barriers) ----------------
// 512 blocks x 16-row strips; 4 waves col-split (wave w = 64-col window cc = c*4+w).
// Per chunk per wave: 1 u64 bits load (128B/wave, L2) + 8 B-frag (WhTp 1MB L2-resident)
// + 4 Wh2 float4 (32KB L2). Mask stream GONE from this kernel (decoupled to k_maskbits):
// no DMA, no LDS staging, no barriers in the loop -> 16 waves/CU (launch_bounds 256,4),
// latency hidden by TLP. Full row per block -> softmax finished in-block, no k_finish.
__global__ __launch_bounds__(256, 4) void k_attn(const unsigned long long* __restrict__ bits,
                                                 const unsigned short* __restrict__ WhTp,
                                                 const float* __restrict__ Wh1,
                                                 const float* __restrict__ Wh2,
                                                 float* __restrict__ out) {
    __shared__ float accbuf[4][16][68];
    __shared__ float lsumbuf[4][16];

    const int tid  = threadIdx.x;
    const int wave = tid >> 6;
    const int lane = tid & 63;
    const int i16 = lane & 15;
    const int g   = lane >> 4;
    const int R   = blockIdx.x * 16;

    const float wh1v = Wh1[R + i16];
    const unsigned long long* bstrip = bits + (size_t)blockIdx.x * 2048 + i16;

    f32x4 acc0 = {0.f,0.f,0.f,0.f}, acc1 = {0.f,0.f,0.f,0.f};
    f32x4 acc2 = {0.f,0.f,0.f,0.f}, acc3 = {0.f,0.f,0.f,0.f};
    float lsum = 0.f;

    #pragma unroll 2
    for (int c = 0; c < 32; ++c) {
        const int cc = c * 4 + wave;

        const unsigned long long bw = bstrip[(size_t)cc * 16];
        const unsigned short* bb = WhTp + (size_t)i16 * N_NODES + cc * 64 + g * 8;
        const bf16x8 B0 = *(const bf16x8*)(bb);
        const bf16x8 B1 = *(const bf16x8*)(bb + 32);
        const bf16x8 B2 = *(const bf16x8*)(bb + 16 * N_NODES);
        const bf16x8 B3 = *(const bf16x8*)(bb + 16 * N_NODES + 32);
        const bf16x8 B4 = *(const bf16x8*)(bb + 32 * N_NODES);
        const bf16x8 B5 = *(const bf16x8*)(bb + 32 * N_NODES + 32);
        const bf16x8 B6 = *(const bf16x8*)(bb + 48 * N_NODES);
        const bf16x8 B7 = *(const bf16x8*)(bb + 48 * N_NODES + 32);
        const float* wp = Wh2 + cc * 64 + g * 4;
        const float4 W0 = *(const float4*)(wp);
        const float4 W1 = *(const float4*)(wp + 16);
        const float4 W2 = *(const float4*)(wp + 32);
        const float4 W3 = *(const float4*)(wp + 48);

        // bits for this lane: af0 uses cols g*4+{0..3} (+16), af1 uses +32, +48
        const unsigned lo = (unsigned)(bw >> (g * 4));        // positions 0..3, 16..19
        const unsigned hi = (unsigned)(bw >> (g * 4 + 32));   // positions 0..3, 16..19

        bf16x8 af0, af1;
        af0[0] = (short)f2bf(pb(lo,  0, W0.x, wh1v, lsum));
        af0[1] = (short)f2bf(pb(lo,  1, W0.y, wh1v, lsum));
        af0[2] = (short)f2bf(pb(lo,  2, W0.z, wh1v, lsum));
        af0[3] = (short)f2bf(pb(lo,  3, W0.w, wh1v, lsum));
        af0[4] = (short)f2bf(pb(lo, 16, W1.x, wh1v, lsum));
        af0[5] = (short)f2bf(pb(lo, 17, W1.y, wh1v, lsum));
        af0[6] = (short)f2bf(pb(lo, 18, W1.z, wh1v, lsum));
        af0[7] = (short)f2bf(pb(lo, 19, W1.w, wh1v, lsum));
        af1[0] = (short)f2bf(pb(hi,  0, W2.x, wh1v, lsum));
        af1[1] = (short)f2bf(pb(hi,  1, W2.y, wh1v, lsum));
        af1[2] = (short)f2bf(pb(hi,  2, W2.z, wh1v, lsum));
        af1[3] = (short)f2bf(pb(hi,  3, W2.w, wh1v, lsum));
        af1[4] = (short)f2bf(pb(hi, 16, W3.x, wh1v, lsum));
        af1[5] = (short)f2bf(pb(hi, 17, W3.y, wh1v, lsum));
        af1[6] = (short)f2bf(pb(hi, 18, W3.z, wh1v, lsum));
        af1[7] = (short)f2bf(pb(hi, 19, W3.w, wh1v, lsum));

        acc0 = __builtin_amdgcn_mfma_f32_16x16x32_bf16(af0, B0, acc0, 0, 0, 0);
        acc1 = __builtin_amdgcn_mfma_f32_16x16x32_bf16(af0, B2, acc1, 0, 0, 0);
        acc2 = __builtin_amdgcn_mfma_f32_16x16x32_bf16(af0, B4, acc2, 0, 0, 0);
        acc3 = __builtin_amdgcn_mfma_f32_16x16x32_bf16(af0, B6, acc3, 0, 0, 0);
        acc0 = __builtin_amdgcn_mfma_f32_16x16x32_bf16(af1, B1, acc0, 0, 0, 0);
        acc1 = __builtin_amdgcn_mfma_f32_16x16x32_bf16(af1, B3, acc1, 0, 0, 0);
        acc2 = __builtin_amdgcn_mfma_f32_16x16x32_bf16(af1, B5, acc2, 0, 0, 0);
        acc3 = __builtin_amdgcn_mfma_f32_16x16x32_bf16(af1, B7, acc3, 0, 0, 0);
    }

    // lsum: sum the 4 g-subgroups holding the same row
    lsum += __shfl_xor(lsum, 16);
    lsum += __shfl_xor(lsum, 32);

    // D layout (m89): row = g*4 + r, col = i16
    #pragma unroll
    for (int r = 0; r < 4; ++r) {
        accbuf[wave][g*4 + r][ 0 + i16] = acc0[r];
        accbuf[wave][g*4 + r][16 + i16] = acc1[r];
        accbuf[wave][g*4 + r][32 + i16] = acc2[r];
        accbuf[wave][g*4 + r][48 + i16] = acc3[r];
    }
    if (lane < 16) lsumbuf[wave][lane] = lsum;
    __syncthreads();

    // merge 4 waves (disjoint col-windows), normalize, ELU, store
    const int tr  = tid >> 4;
    const int tf4 = (tid & 15) * 4;
    float4 s0 = *(const float4*)&accbuf[0][tr][tf4];
    float4 s1 = *(const float4*)&accbuf[1][tr][tf4];
    float4 s2 = *(const float4*)&accbuf[2][tr][tf4];
    float4 s3 = *(const float4*)&accbuf[3][tr][tf4];
    float L = lsumbuf[0][tr] + lsumbuf[1][tr] + lsumbuf[2][tr] + lsumbuf[3][tr];
    const float inv = (L > 0.f) ? 1.f / L : 0.f;
    float4 o;
    o.x = (s0.x + s1.x + s2.x + s3.x) * inv;
    o.y = (s0.y + s1.y + s2.y + s3.y) * inv;
    o.z = (s0.z + s1.z + s2.z + s3.z) * inv;
    o.w = (s0.w + s1.w + s2.w + s3.w) * inv;
    o.x = (o.x > 0.f) ? o.x : (__expf(o.x) - 1.f);
    o.y = (o.y > 0.f) ? o.y : (__expf(o.y) - 1.f);
    o.z = (o.z > 0.f) ? o.z : (__expf(o.z) - 1.f);
    o.w = (o.w > 0.f) ? o.w : (__expf(o.w) - 1.f);
    *(float4*)&out[(size_t)(R + tr) * D_OUT + tf4] = o;
}

extern "C" void kernel_launch(void* const* d_in, const int* in_sizes, int n_in,
                              void* d_out, int out_size, void* d_ws, size_t ws_size,
                              hipStream_t stream) {
    const float* h    = (const float*)d_in[0];
    const float* mask = (const float*)d_in[1];
    // d_in[2] = lamda: unused (dischange==0 makes the mask-update a no-op)
    const float* W    = (const float*)d_in[3];
    const float* a    = (const float*)d_in[4];
    float* out = (float*)d_out;

    // ws: WhTp bf16 [64][8192] (1MB) | Wh1 (32KB) | Wh2 (32KB) | bits u64 [512][128][16] (8MB)
    unsigned short* WhTp = (unsigned short*)d_ws;
    float* Wh1 = (float*)((char*)d_ws + (size_t)D_OUT * N_NODES * sizeof(unsigned short));
    float* Wh2 = Wh1 + N_NODES;
    unsigned long long* bitsw = (unsigned long long*)(Wh2 + N_NODES);

    k_gemm_wh<<<N_NODES / 32, 256, 0, stream>>>(h, W, a, WhTp, Wh1, Wh2);
    k_maskbits<<<N_NODES / 4, 256, 0, stream>>>(mask, bitsw);
    k_attn<<<N_NODES / 16, 256, 0, stream>>>(bitsw, WhTp, Wh1, Wh2, out);
}

// Round 16
// 141.414 us; speedup vs baseline: 4.7187x; 1.0161x over previous
//
#include <hip/hip_runtime.h>

#define N_NODES 8192
#define D_IN 512
#define D_OUT 64
#define LRELU_ALPHA 0.2f

typedef __attribute__((ext_vector_type(8))) short bf16x8;
typedef __attribute__((ext_vector_type(4))) float f32x4;

__device__ __forceinline__ unsigned short f2bf(float x) {
    unsigned u = __float_as_uint(x);
    u += 0x7fffu + ((u >> 16) & 1u);   // round-to-nearest-even
    return (unsigned short)(u >> 16);
}

// bit-gated p: e = lrelu(wh1+w2); p = bit ? exp(e) : 0
__device__ __forceinline__ float pb(unsigned bits, int pos, float w2v, float wh1v, float& lsum) {
    float e = wh1v + w2v;
    e = fmaxf(e, LRELU_ALPHA * e);
    float p = ((bits >> pos) & 1u) ? __expf(e) : 0.f;
    lsum += p;
    return p;
}

// ---------------- Kernel 0: mask f32 (256MB) -> bitmask (8MB), VECTORIZED ----------------
// Lane reads float4 (16B/lane, 1KB/wave/instr -- the m13 BW pattern; R15's scalar loads
// were the ~2x loss). Ballot of component d: bit l <-> col q*256 + 4l + d (interleaved
// order; consumer adapts). Layout: bits[strip][q][row16][word d] -> consumer lane reads
// 32B contiguous. 2048 blocks = 8/CU = full streaming occupancy.
__global__ __launch_bounds__(256) void k_maskbits(const float* __restrict__ mask,
                                                  unsigned long long* __restrict__ bits) {
    const int wave = threadIdx.x >> 6;
    const int lane = threadIdx.x & 63;
    const int row = blockIdx.x * 4 + wave;
    const float4* m4 = (const float4*)(mask + (size_t)row * N_NODES);
    const int strip = row >> 4;
    const int r16 = row & 15;
    #pragma unroll 4
    for (int q = 0; q < 32; ++q) {
        const float4 v = m4[q * 64 + lane];
        const unsigned long long b0 = __ballot(v.x > 0.f);
        const unsigned long long b1 = __ballot(v.y > 0.f);
        const unsigned long long b2 = __ballot(v.z > 0.f);
        const unsigned long long b3 = __ballot(v.w > 0.f);
        if (lane == 0) {
            unsigned long long* dst = bits + (((size_t)strip * 32 + q) * 16 + r16) * 4;
            ulonglong2 t0; t0.x = b0; t0.y = b1;
            ulonglong2 t1; t1.x = b2; t1.y = b3;
            *(ulonglong2*)(dst)     = t0;
            *(ulonglong2*)(dst + 2) = t1;
        }
    }
}

// ---------------- Kernel 1: Wh = h @ W; epilogue writes WhTp(bf16, frag-order), Wh1, Wh2 ----------------
__global__ __launch_bounds__(256) void k_gemm_wh(const float* __restrict__ h,
                                                 const float* __restrict__ W,
                                                 const float* __restrict__ a,
                                                 unsigned short* __restrict__ WhTp,
                                                 float* __restrict__ Wh1,
                                                 float* __restrict__ Wh2) {
    __shared__ float hs[32][68];
    __shared__ float Ws[64][64];
    const int tid = threadIdx.x;
    const int r0 = blockIdx.x * 32;
    const int tf = tid & 15;
    const int tr = tid >> 4;
    float acc[2][4] = {{0.f,0.f,0.f,0.f},{0.f,0.f,0.f,0.f}};

    for (int kc = 0; kc < D_IN; kc += 64) {
        {
            int rr = tid >> 4;
            int cc = (tid & 15) * 4;
            float4 v0 = *(const float4*)&h[(size_t)(r0 + rr) * D_IN + kc + cc];
            float4 v1 = *(const float4*)&h[(size_t)(r0 + rr + 16) * D_IN + kc + cc];
            *(float4*)&hs[rr][cc] = v0;
            *(float4*)&hs[rr + 16][cc] = v1;
        }
        #pragma unroll
        for (int p = 0; p < 4; ++p) {
            int kk = (tid >> 4) + p * 16;
            int cc = (tid & 15) * 4;
            *(float4*)&Ws[kk][cc] = *(const float4*)&W[(size_t)(kc + kk) * D_OUT + cc];
        }
        __syncthreads();
        #pragma unroll
        for (int k = 0; k < 64; k += 4) {
            float4 a0 = *(const float4*)&hs[tr*2][k];
            float4 a1 = *(const float4*)&hs[tr*2+1][k];
            float av0[4] = {a0.x, a0.y, a0.z, a0.w};
            float av1[4] = {a1.x, a1.y, a1.z, a1.w};
            #pragma unroll
            for (int kk = 0; kk < 4; ++kk) {
                float4 b = *(const float4*)&Ws[k+kk][tf*4];
                acc[0][0] += av0[kk]*b.x; acc[0][1] += av0[kk]*b.y;
                acc[0][2] += av0[kk]*b.z; acc[0][3] += av0[kk]*b.w;
                acc[1][0] += av1[kk]*b.x; acc[1][1] += av1[kk]*b.y;
                acc[1][2] += av1[kk]*b.z; acc[1][3] += av1[kk]*b.w;
            }
        }
        __syncthreads();
    }
    const int orow = r0 + tr*2;   // even

    // permuted WhTp write: each MFMA B fragment is one contiguous 16B
    {
        const int blk = orow >> 6;
        const int cw  = orow & 63;
        const int d   = cw & 3;
        const int gg  = (cw >> 2) & 3;
        const int m   = cw >> 4;
        const int soff = blk * 64 + (m >> 1) * 32 + gg * 8 + (m & 1) * 4 + d;
        #pragma unroll
        for (int k = 0; k < 4; ++k) {
            unsigned v = (unsigned)f2bf(acc[0][k]) | ((unsigned)f2bf(acc[1][k]) << 16);
            *(unsigned*)&WhTp[(size_t)(tf*4 + k) * N_NODES + soff] = v;
        }
    }

    float a1v[4], a2v[4];
    #pragma unroll
    for (int k = 0; k < 4; ++k) { a1v[k] = a[tf*4 + k]; a2v[k] = a[64 + tf*4 + k]; }
    float s1 = 0.f, t1 = 0.f, s2 = 0.f, t2 = 0.f;
    #pragma unroll
    for (int k = 0; k < 4; ++k) {
        s1 += acc[0][k] * a1v[k];
        t1 += acc[1][k] * a1v[k];
        s2 += acc[0][k] * a2v[k];
        t2 += acc[1][k] * a2v[k];
    }
    #pragma unroll
    for (int d = 1; d < 16; d <<= 1) {
        s1 += __shfl_xor(s1, d);
        t1 += __shfl_xor(t1, d);
        s2 += __shfl_xor(s2, d);
        t2 += __shfl_xor(t2, d);
    }
    if (tf == 0) {
        Wh1[orow] = s1; Wh1[orow + 1] = t1;
        Wh2[orow] = s2; Wh2[orow + 1] = t2;
    }
}

// ---------------- Kernel 2: bit-gated masked-softmax + PV via MFMA, 8 waves/block ----------------
// 512 blocks x 512 threads (8 waves) = 16 waves/CU -- 2x R15's grid-limited 8 (the
// diagnosed latency gap). Wave w owns 64-col windows cc = c*8 + w, c in [0,16). Per
// chunk per wave: 2 ulonglong2 bit loads (32B/lane contiguous, L2) + 8 B-frags (WhTp
// 1MB, L2-resident) + 4 Wh2 float4 (32KB, L2). Interleaved bit order: sub = w&3 fixed
// per wave; u_d = word_d >> (sub*16+g); element (m,d) gate = bit 4m of u_d. No LDS in
// the loop, no barriers, register-only body. Full row per block -> softmax in-block.
__global__ __launch_bounds__(512, 4) void k_attn(const unsigned long long* __restrict__ bits,
                                                 const unsigned short* __restrict__ WhTp,
                                                 const float* __restrict__ Wh1,
                                                 const float* __restrict__ Wh2,
                                                 float* __restrict__ out) {
    __shared__ float accbuf[8][16][68];
    __shared__ float lsumbuf[8][16];

    const int tid  = threadIdx.x;
    const int wave = tid >> 6;       // 0..7
    const int lane = tid & 63;
    const int i16 = lane & 15;
    const int g   = lane >> 4;
    const int R   = blockIdx.x * 16;
    const int strip = blockIdx.x;

    const float wh1v = Wh1[R + i16];
    const int sub = wave & 3;
    const int qw  = wave >> 2;
    const int sh  = sub * 16 + g;

    f32x4 acc0 = {0.f,0.f,0.f,0.f}, acc1 = {0.f,0.f,0.f,0.f};
    f32x4 acc2 = {0.f,0.f,0.f,0.f}, acc3 = {0.f,0.f,0.f,0.f};
    float lsum = 0.f;

    for (int c = 0; c < 16; ++c) {
        const int cc = c * 8 + wave;       // 64-col window
        const int q  = 2 * c + qw;         // 256-col group

        const unsigned long long* wp_ = bits + (((size_t)strip * 32 + q) * 16 + i16) * 4;
        const ulonglong2 Wd01 = *(const ulonglong2*)(wp_);
        const ulonglong2 Wd23 = *(const ulonglong2*)(wp_ + 2);
        const unsigned u0 = (unsigned)(Wd01.x >> sh);
        const unsigned u1 = (unsigned)(Wd01.y >> sh);
        const unsigned u2 = (unsigned)(Wd23.x >> sh);
        const unsigned u3 = (unsigned)(Wd23.y >> sh);

        const unsigned short* bb = WhTp + (size_t)i16 * N_NODES + cc * 64 + g * 8;
        const bf16x8 B0 = *(const bf16x8*)(bb);
        const bf16x8 B1 = *(const bf16x8*)(bb + 32);
        const bf16x8 B2 = *(const bf16x8*)(bb + 16 * N_NODES);
        const bf16x8 B3 = *(const bf16x8*)(bb + 16 * N_NODES + 32);
        const bf16x8 B4 = *(const bf16x8*)(bb + 32 * N_NODES);
        const bf16x8 B5 = *(const bf16x8*)(bb + 32 * N_NODES + 32);
        const bf16x8 B6 = *(const bf16x8*)(bb + 48 * N_NODES);
        const bf16x8 B7 = *(const bf16x8*)(bb + 48 * N_NODES + 32);
        const float* wp = Wh2 + cc * 64 + g * 4;
        const float4 W0 = *(const float4*)(wp);
        const float4 W1 = *(const float4*)(wp + 16);
        const float4 W2 = *(const float4*)(wp + 32);
        const float4 W3 = *(const float4*)(wp + 48);

        // element (m, d): col = cc*64 + m*16 + g*4 + d; gate = bit 4m of u_d
        bf16x8 af0, af1;
        af0[0] = (short)f2bf(pb(u0,  0, W0.x, wh1v, lsum));
        af0[1] = (short)f2bf(pb(u1,  0, W0.y, wh1v, lsum));
        af0[2] = (short)f2bf(pb(u2,  0, W0.z, wh1v, lsum));
        af0[3] = (short)f2bf(pb(u3,  0, W0.w, wh1v, lsum));
        af0[4] = (short)f2bf(pb(u0,  4, W1.x, wh1v, lsum));
        af0[5] = (short)f2bf(pb(u1,  4, W1.y, wh1v, lsum));
        af0[6] = (short)f2bf(pb(u2,  4, W1.z, wh1v, lsum));
        af0[7] = (short)f2bf(pb(u3,  4, W1.w, wh1v, lsum));
        af1[0] = (short)f2bf(pb(u0,  8, W2.x, wh1v, lsum));
        af1[1] = (short)f2bf(pb(u1,  8, W2.y, wh1v, lsum));
        af1[2] = (short)f2bf(pb(u2,  8, W2.z, wh1v, lsum));
        af1[3] = (short)f2bf(pb(u3,  8, W2.w, wh1v, lsum));
        af1[4] = (short)f2bf(pb(u0, 12, W3.x, wh1v, lsum));
        af1[5] = (short)f2bf(pb(u1, 12, W3.y, wh1v, lsum));
        af1[6] = (short)f2bf(pb(u2, 12, W3.z, wh1v, lsum));
        af1[7] = (short)f2bf(pb(u3, 12, W3.w, wh1v, lsum));

        acc0 = __builtin_amdgcn_mfma_f32_16x16x32_bf16(af0, B0, acc0, 0, 0, 0);
        acc1 = __builtin_amdgcn_mfma_f32_16x16x32_bf16(af0, B2, acc1, 0, 0, 0);
        acc2 = __builtin_amdgcn_mfma_f32_16x16x32_bf16(af0, B4, acc2, 0, 0, 0);
        acc3 = __builtin_amdgcn_mfma_f32_16x16x32_bf16(af0, B6, acc3, 0, 0, 0);
        acc0 = __builtin_amdgcn_mfma_f32_16x16x32_bf16(af1, B1, acc0, 0, 0, 0);
        acc1 = __builtin_amdgcn_mfma_f32_16x16x32_bf16(af1, B3, acc1, 0, 0, 0);
        acc2 = __builtin_amdgcn_mfma_f32_16x16x32_bf16(af1, B5, acc2, 0, 0, 0);
        acc3 = __builtin_amdgcn_mfma_f32_16x16x32_bf16(af1, B7, acc3, 0, 0, 0);
    }

    // lsum: sum the 4 g-subgroups holding the same row
    lsum += __shfl_xor(lsum, 16);
    lsum += __shfl_xor(lsum, 32);

    // D layout (m89): row = g*4 + r, col = i16
    #pragma unroll
    for (int r = 0; r < 4; ++r) {
        accbuf[wave][g*4 + r][ 0 + i16] = acc0[r];
        accbuf[wave][g*4 + r][16 + i16] = acc1[r];
        accbuf[wave][g*4 + r][32 + i16] = acc2[r];
        accbuf[wave][g*4 + r][48 + i16] = acc3[r];
    }
    if (lane < 16) lsumbuf[wave][lane] = lsum;
    __syncthreads();

    // merge 8 waves (disjoint col-windows), normalize, ELU, store
    if (tid < 256) {
        const int tr  = tid >> 4;
        const int tf4 = (tid & 15) * 4;
        float4 s = {0.f, 0.f, 0.f, 0.f};
        float L = 0.f;
        #pragma unroll
        for (int w = 0; w < 8; ++w) {
            float4 v = *(const float4*)&accbuf[w][tr][tf4];
            s.x += v.x; s.y += v.y; s.z += v.z; s.w += v.w;
            L += lsumbuf[w][tr];
        }
        const float inv = (L > 0.f) ? 1.f / L : 0.f;
        float4 o;
        o.x = s.x * inv; o.y = s.y * inv; o.z = s.z * inv; o.w = s.w * inv;
        o.x = (o.x > 0.f) ? o.x : (__expf(o.x) - 1.f);
        o.y = (o.y > 0.f) ? o.y : (__expf(o.y) - 1.f);
        o.z = (o.z > 0.f) ? o.z : (__expf(o.z) - 1.f);
        o.w = (o.w > 0.f) ? o.w : (__expf(o.w) - 1.f);
        *(float4*)&out[(size_t)(R + tr) * D_OUT + tf4] = o;
    }
}

extern "C" void kernel_launch(void* const* d_in, const int* in_sizes, int n_in,
                              void* d_out, int out_size, void* d_ws, size_t ws_size,
                              hipStream_t stream) {
    const float* h    = (const float*)d_in[0];
    const float* mask = (const float*)d_in[1];
    // d_in[2] = lamda: unused (dischange==0 makes the mask-update a no-op)
    const float* W    = (const float*)d_in[3];
    const float* a    = (const float*)d_in[4];
    float* out = (float*)d_out;

    // ws: WhTp bf16 [64][8192] (1MB) | Wh1 (32KB) | Wh2 (32KB) | bits u64 [512][32][16][4] (8MB)
    unsigned short* WhTp = (unsigned short*)d_ws;
    float* Wh1 = (float*)((char*)d_ws + (size_t)D_OUT * N_NODES * sizeof(unsigned short));
    float* Wh2 = Wh1 + N_NODES;
    unsigned long long* bitsw = (unsigned long long*)(Wh2 + N_NODES);

    k_gemm_wh<<<N_NODES / 32, 256, 0, stream>>>(h, W, a, WhTp, Wh1, Wh2);
    k_maskbits<<<N_NODES / 4, 256, 0, stream>>>(mask, bitsw);
    k_attn<<<N_NODES / 16, 512, 0, stream>>>(bitsw, WhTp, Wh1, Wh2, out);
}